// Round 4
// baseline (39.086 us; speedup 1.0000x reference)
//
#include <hip/hip_runtime.h>

// Problem constants (b=4, n=64, d=64, E=4096)
// zt  layout: [b][d][i][k] -> ((b*64+d)*64+i)*64+k   (4 MB)
// zt2: tropical output, same layout (4 MB)
// a1[r][e], a3[r][e] : r = b*64+i (node row), 64 KB each
//
// Design: no LDS in any compute loop. Per-lane operand lives in a 64-deep
// VGPR column (coalesced loads); wave-uniform operand streams through SGPRs
// (s_load via readfirstlane-uniform addresses). Inner loops are pure VALU.

__device__ __forceinline__ int rfl(int x) { return __builtin_amdgcn_readfirstlane(x); }

// K1: z = pe@Whz + b, stored transposed. grid = 1024: (bi, k-quarter)
__global__ __launch_bounds__(256) void k_pathlin(
    const float* __restrict__ pe, const float* __restrict__ Whz,
    const float* __restrict__ bhz, float* __restrict__ zt) {
  int blk = blockIdx.x;
  int bi = blk >> 2, q = blk & 3;
  int b = bi >> 6, i = bi & 63;
  int t = threadIdx.x, lane = t & 63;
  int g = rfl(t >> 6);                    // SGPR wave id
  // W column in VGPRs: wreg[c] = Whz[c][lane]  (coalesced, L2-hot)
  float wreg[64];
#pragma unroll
  for (int c = 0; c < 64; ++c) wreg[c] = Whz[c * 64 + lane];
  // pe rows for this wave's 4 k: wave-uniform address -> s_load stream
  const float* rowbase = pe + (size_t)bi * 4096 + (size_t)(q * 16 + g * 4) * 64;
  float bv = bhz[lane];
  float acc0 = bv, acc1 = bv, acc2 = bv, acc3 = bv;
#pragma unroll
  for (int c = 0; c < 64; ++c) {
    float w = wreg[c];
    acc0 += rowbase[c] * w;
    acc1 += rowbase[64 + c] * w;
    acc2 += rowbase[128 + c] * w;
    acc3 += rowbase[192 + c] * w;
  }
  // transposed store: d = lane, 4 consecutive k -> one float4
  float* dst = zt + (size_t)b * 262144 + (size_t)lane * 4096
             + (size_t)i * 64 + q * 16 + g * 4;
  *(float4*)dst = make_float4(acc0, acc1, acc2, acc3);
}

// K2: blocks [0,1024): tropical quarter-slices (no LDS);
//     blocks [1024,1280): node MLP + nodeproj (LDS elist only)
__global__ __launch_bounds__(256) void k_trop_node(
    const float* __restrict__ zt, float* __restrict__ zt2,
    const float* __restrict__ ne, const int* __restrict__ eidx,
    const float* __restrict__ Wzz, const float* __restrict__ Wnm,
    const float* __restrict__ bnm,
    float* __restrict__ a1, float* __restrict__ a3, float* __restrict__ out0) {
  int t = threadIdx.x, lane = t & 63;
  int g = rfl(t >> 6);                    // SGPR wave id
  __shared__ float shA[4][1024];          // node branch only (elist)
  __shared__ float part[4][64];
  __shared__ float nlal[2][64];
  if (blockIdx.x < 1024) {
    int slice = blockIdx.x >> 2, iq = blockIdx.x & 3;   // slice = b*64+d
    const float* Ag = zt + (size_t)slice * 4096;
    // column A[k][lane] in VGPRs (coalesced)
    float colreg[64];
#pragma unroll
    for (int k = 0; k < 64; ++k) colreg[k] = Ag[k * 64 + lane];
    int i0 = iq * 16 + g * 4;
    const float* rb = Ag + (size_t)i0 * 64;             // uniform -> s_load
    // init with z itself (max(z_conv, z))
    float acc0 = rb[lane];                               // row i0+0, col lane
    float acc1 = rb[64 + lane];
    float acc2 = rb[128 + lane];
    float acc3 = rb[192 + lane];
#pragma unroll
    for (int k = 0; k < 64; ++k) {
      float c = colreg[k];
      acc0 = fmaxf(acc0, rb[k] + c);
      acc1 = fmaxf(acc1, rb[64 + k] + c);
      acc2 = fmaxf(acc2, rb[128 + k] + c);
      acc3 = fmaxf(acc3, rb[192 + k] + c);
    }
    float* Og = zt2 + (size_t)slice * 4096 + (size_t)i0 * 64;
    Og[lane] = acc0;
    Og[64 + lane] = acc1;
    Og[128 + lane] = acc2;
    Og[192 + lane] = acc3;
  } else {
    int r = blockIdx.x - 1024;
    int* elist = (int*)&shA[0][0];        // 4096 ints, wave-segmented
    const int* srcv = eidx;
    const int* dstv = eidx + 4096;
    int cntw = 0;
    unsigned long long ltmask = (lane == 63) ? 0x7fffffffffffffffull
                                             : ((1ull << lane) - 1ull);
    for (int q = 0; q < 16; ++q) {
      int e2 = g * 1024 + q * 64 + lane;
      bool match = (dstv[e2] == r);
      unsigned long long mask = __ballot(match);
      if (match) {
        int pos = cntw + __popcll(mask & ltmask);
        elist[g * 1024 + pos] = srcv[e2];
      }
      cntw += __popcll(mask);
    }
    float accA = 0.f;
    for (int m = 0; m < cntw; ++m) accA += ne[elist[g * 1024 + m] * 64 + lane];
    part[g][lane] = accA;
    if (g == 0) nlal[0][lane] = ne[r * 64 + lane];
    __syncthreads();
    if (g == 0)
      nlal[1][lane] = part[0][lane] + part[1][lane] + part[2][lane] + part[3][lane];
    __syncthreads();
    float s = 0.f;
    for (int d2 = g * 16; d2 < g * 16 + 16; ++d2) {
      s += nlal[0][d2] * Wnm[d2 * 64 + lane]
         + nlal[1][d2] * Wnm[(64 + d2) * 64 + lane];
    }
    part[g][lane] = s;
    if (g == 0) {
      const float* nr = ne + r * 64;
      float s1 = 0.f;
      for (int d2 = 0; d2 < 64; ++d2) s1 += nr[d2] * Wzz[d2 * 64 + lane];
      a1[r * 64 + lane] = s1;
    } else if (g == 1) {
      const float* nr = ne + r * 64;
      float s3 = 0.f;
      for (int d2 = 0; d2 < 64; ++d2) s3 += nr[d2] * Wzz[(128 + d2) * 64 + lane];
      a3[r * 64 + lane] = s3;
    }
    __syncthreads();
    if (g == 0) {
      float v = part[0][lane] + part[1][lane] + part[2][lane] + part[3][lane]
                + bnm[lane];
      v = fmaxf(v, 0.f);
      out0[r * 64 + lane] = v + nlal[0][lane];
    }
  }
}

// K3: u_path. grid = 1024: (bi, j-quarter); wave handles 4 consecutive j.
__global__ __launch_bounds__(256) void k_upath(
    const float* __restrict__ zt2, const float* __restrict__ Wzz,
    const float* __restrict__ bzz, const float* __restrict__ a1,
    const float* __restrict__ a3, const float* __restrict__ pe,
    float* __restrict__ out1) {
  int blk = blockIdx.x;
  int bi = blk >> 2, jq = blk & 3;
  int b = bi >> 6, i = bi & 63;
  int t = threadIdx.x, lane = t & 63;
  int g = rfl(t >> 6);
  // W2 column in VGPRs: w2[d] = Wzz[64+d][lane]  (coalesced, L2-hot)
  float w2[64];
#pragma unroll
  for (int d = 0; d < 64; ++d) w2[d] = Wzz[(64 + d) * 64 + lane];
  int j0 = jq * 16 + g * 4;
  // z values: 4 consecutive j at fixed (d,i) -> one s_load_dwordx4 per d
  const float* zb = zt2 + (size_t)b * 262144 + (size_t)i * 64 + j0;
  float base = a1[bi * 64 + lane] + bzz[lane];
  float acc0 = base, acc1 = base, acc2 = base, acc3 = base;
#pragma unroll
  for (int d = 0; d < 64; ++d) {
    const float* zd = zb + (size_t)d * 4096;             // uniform -> s_load x4
    float w = w2[d];
    acc0 += zd[0] * w;
    acc1 += zd[1] * w;
    acc2 += zd[2] * w;
    acc3 += zd[3] * w;
  }
  const float* a3b = a3 + (size_t)(b * 64) * 64;
  size_t ob = (size_t)bi * 4096 + (size_t)j0 * 64;
  float acc[4] = {acc0, acc1, acc2, acc3};
#pragma unroll
  for (int jj = 0; jj < 4; ++jj) {
    float v = acc[jj] + a3b[(j0 + jj) * 64 + lane];
    v = fmaxf(v, 0.f);
    out1[ob + jj * 64 + lane] = v + pe[ob + jj * 64 + lane];
  }
}

extern "C" void kernel_launch(void* const* d_in, const int* in_sizes, int n_in,
                              void* d_out, int out_size, void* d_ws, size_t ws_size,
                              hipStream_t stream) {
  const float* node = (const float*)d_in[0];
  const float* pe   = (const float*)d_in[1];
  const int*   eidx = (const int*)d_in[2];
  const float* Whz  = (const float*)d_in[3];
  const float* bhz  = (const float*)d_in[4];
  const float* Wzz  = (const float*)d_in[5];
  const float* bzz  = (const float*)d_in[6];
  const float* Wnm  = (const float*)d_in[7];
  const float* bnm  = (const float*)d_in[8];
  float* out0 = (float*)d_out;
  float* out1 = out0 + 16384;
  float* zt  = (float*)d_ws;                // 4 MB
  float* a1  = zt + 1048576;                // 64 KB
  float* a3  = a1 + 16384;                  // 64 KB
  float* zt2 = a3 + 16384;                  // 4 MB

  hipLaunchKernelGGL(k_pathlin, dim3(1024), dim3(256), 0, stream, pe, Whz, bhz, zt);
  hipLaunchKernelGGL(k_trop_node, dim3(1280), dim3(256), 0, stream,
                     zt, zt2, node, eidx, Wzz, Wnm, bnm, a1, a3, out0);
  hipLaunchKernelGGL(k_upath, dim3(1024), dim3(256), 0, stream,
                     zt2, Wzz, bzz, a1, a3, pe, out1);
}